// Round 1
// 198.756 us; speedup vs baseline: 1.0334x; 1.0334x over previous
//
#include <hip/hip_runtime.h>
#include <hip/hip_bf16.h>
#include <hip/hip_fp16.h>
#include <hip/hip_fp8.h>

#define N_NODES  50000
#define N_EDGES  800000
#define D        128
#define N_GRAPHS 64
#define CAP      64          // bucket capacity; in-deg ~ Poisson(16), P(>=64) ~ 1e-19
#define EW_SCALE 1048576.0f  // 2^20 fixed-point for packed weighted-degree
#define NB_GEMM1 391         // ceil(50000/128)
#define NB_FILL  3125        // 800000/256
#define NB_AGG16 3125        // N_NODES/16

typedef _Float16 half8 __attribute__((ext_vector_type(8)));
typedef _Float16 half4 __attribute__((ext_vector_type(4)));
typedef float   float4v __attribute__((ext_vector_type(4)));
typedef float   f32x2   __attribute__((ext_vector_type(2)));

__device__ __forceinline__ float2 h2f(unsigned int u) {
    __half2 h = *reinterpret_cast<__half2*>(&u);
    return __half22float2(h);
}
__device__ __forceinline__ float hu2f(unsigned short u) {
    __half_raw hr; hr.x = u;
    return __half2float(__half(hr));
}
// 2x fp8 e4m3 -> 2x f32 (v_cvt_pk_f32_fp8)
__device__ __forceinline__ float2 fp8x2_f32(unsigned short u) {
    f32x2 v = __builtin_amdgcn_cvt_pk_f32_fp8((int)u, false);
    return make_float2(v[0], v[1]);
}
__device__ __forceinline__ unsigned char f32_fp8(float f) {
    __hip_fp8_e4m3 q(f);
    return (unsigned char)q.__x;
}
// unpack packed word -> (cnt, dinv)
__device__ __forceinline__ void unpack_pd(unsigned long long p, int& n, float& dv) {
    int c = (int)(p >> 40);
    n = c < CAP ? c : CAP;
    dv = rsqrtf(1.0f + (float)(p & 0xFFFFFFFFFFULL) * (1.0f / EW_SCALE));
}

// ---------------------------------------------------------------------------
// FUSED: blocks [0,391) = gemm1 (x @ W1 -> FP8 e4m3) now on the MFMA pipe:
// fp16 staging (fp8-output quantization dominates fp16 rounding), 16x16x32
// f16 MFMA, K-tiled BK=32, LDS pitch 72 halfs (144 B, 16B-aligned b128 reads,
// 2-way bank alias = free). Frees the VALU for the fill waves so the kernel
// settles at the ~53 us returning-atomic floor instead of 64 us.
// blocks [391,3516) = fill (1 edge/thread, returning 64-bit atomic on 50K
// spread counters — chip-wide ~15G atomics/s floor). Bucket: src:u16|ew:fp16.
// ---------------------------------------------------------------------------
__global__ __launch_bounds__(256) void fused_gemm1_fill(const float* __restrict__ X,
                                                        const float* __restrict__ W,
                                                        unsigned char* __restrict__ Y8,
                                                        const int* __restrict__ ei,
                                                        const float* __restrict__ ew,
                                                        unsigned long long* __restrict__ packed,
                                                        unsigned int* __restrict__ bucket) {
    __shared__ _Float16 Xs[128][72];  // 18 KB, pitch 144 B
    __shared__ _Float16 Wt[128][72];  // 18 KB, transposed W1 (col-major)

    if (blockIdx.x >= NB_GEMM1) {
        int e = (blockIdx.x - NB_GEMM1) * 256 + threadIdx.x;
        if (e >= N_EDGES) return;
        int r = ei[e];
        int c = ei[N_EDGES + e];
        float w = ew[e];
        unsigned long long add = (1ULL << 40) | (unsigned long long)(unsigned)(w * EW_SCALE + 0.5f);
        unsigned long long old = atomicAdd(&packed[c], add);
        unsigned pos = (unsigned)(old >> 40);
        if (pos < CAP) {
            unsigned short wh = __half_as_ushort(__float2half_rn(w));
            bucket[(size_t)c * CAP + pos] = (unsigned)r | ((unsigned)wh << 16);
        }
        return;
    }

    const int tid  = threadIdx.x;
    const int row0 = blockIdx.x * 128;
    const int wv   = tid >> 6;        // 0..3 : col-tile pair (cols wv*32..wv*32+31)
    const int lane = tid & 63;
    const int quad = lane >> 4;
    const int l16  = lane & 15;

    float4v acc[8][2] = {};

    for (int kt = 0; kt < 4; kt++) {
        const int kbase = kt * 32;
        // stage X rows (fp32 -> fp16), 128 rows x 32 k
        {
            int r  = tid >> 1;
            int rr = row0 + r; if (rr >= N_NODES) rr = N_NODES - 1;
            int k0 = (tid & 1) * 16;
            const float4* src = (const float4*)(X + (size_t)rr * 128 + kbase + k0);
#pragma unroll
            for (int i = 0; i < 4; i++) {
                float4 v = src[i];
                half4 hv;
                hv[0] = (_Float16)v.x; hv[1] = (_Float16)v.y;
                hv[2] = (_Float16)v.z; hv[3] = (_Float16)v.w;
                *(half4*)(&Xs[r][k0 + i * 4]) = hv;
            }
        }
        // stage W transposed (fp32 row-major -> fp16 col-major)
        {
            int k  = tid >> 3;               // 0..31
            int c0 = (tid & 7) * 16;
            const float4* src = (const float4*)(W + (size_t)(kbase + k) * 128 + c0);
#pragma unroll
            for (int i = 0; i < 4; i++) {
                float4 v = src[i];
                Wt[c0 + i * 4 + 0][k] = (_Float16)v.x;
                Wt[c0 + i * 4 + 1][k] = (_Float16)v.y;
                Wt[c0 + i * 4 + 2][k] = (_Float16)v.z;
                Wt[c0 + i * 4 + 3][k] = (_Float16)v.w;
            }
        }
        __syncthreads();

        half8 b0 = *(const half8*)(&Wt[wv * 32 + l16][quad * 8]);
        half8 b1f = *(const half8*)(&Wt[wv * 32 + 16 + l16][quad * 8]);
#pragma unroll
        for (int rt = 0; rt < 8; rt++) {
            half8 a = *(const half8*)(&Xs[rt * 16 + l16][quad * 8]);
            acc[rt][0] = __builtin_amdgcn_mfma_f32_16x16x32_f16(a, b0,  acc[rt][0], 0, 0, 0);
            acc[rt][1] = __builtin_amdgcn_mfma_f32_16x16x32_f16(a, b1f, acc[rt][1], 0, 0, 0);
        }
        __syncthreads();
    }
    // C layout: row = rt*16 + quad*4 + r, col = wv*32 + ct*16 + l16
#pragma unroll
    for (int rt = 0; rt < 8; rt++)
#pragma unroll
        for (int ct = 0; ct < 2; ct++)
#pragma unroll
            for (int r = 0; r < 4; r++) {
                int row = row0 + rt * 16 + quad * 4 + r;
                if (row < N_NODES)
                    Y8[(size_t)row * 128 + wv * 32 + ct * 16 + l16] = f32_fp8(acc[rt][ct][r]);
            }
}

// ---------------------------------------------------------------------------
// Layer-1 agg + row-local gemm2. 512 threads = 8 waves; 16 nodes/block.
// Each wave INTERLEAVES its 2 nodes with 8-edge chunks: 16 independent
// gathers in flight per chunk (2x MLP vs previous 8) — the gather is
// exposed-latency-bound (x8 is L2-resident, 1.7 TB/s << 34 TB/s L2).
// Zero-pad trick: pk=0 beyond n -> val 0, harmless row-0 gather; one loop to
// max(nA,nB). h1 staged fp16 in LDS; MFMA col-tile wv; x2' written FP8.
// ---------------------------------------------------------------------------
__global__ __launch_bounds__(512) void agg1_gemm2_kernel(const unsigned char* __restrict__ x8in,
                                                         const unsigned long long* __restrict__ packed,
                                                         const unsigned int* __restrict__ bucket,
                                                         const float* __restrict__ b1,
                                                         const float* __restrict__ W2,
                                                         unsigned char* __restrict__ x2) {
    __shared__ _Float16 sh1[16][136];
    const int wv   = threadIdx.x >> 6;     // 0..7
    const int lane = threadIdx.x & 63;
    const unsigned short* xs16 = (const unsigned short*)x8in;  // 2 fp8 per ushort
    const int node0 = blockIdx.x * 16;

    float2 bb = ((const float2*)b1)[lane];

    const int nodeA = node0 + wv * 2;
    const int nodeB = nodeA + 1;
    int nA; float dvA; unpack_pd(packed[nodeA], nA, dvA);
    int nB; float dvB; unpack_pd(packed[nodeB], nB, dvB);

    unsigned pkA = 0u, pkB = 0u;
    if (lane < nA) {
        unsigned eh = bucket[(size_t)nodeA * CAP + lane];
        int src = eh & 0xFFFFu;
        int sn; float sdv; unpack_pd(packed[src], sn, sdv);
        float v = hu2f((unsigned short)(eh >> 16)) * sdv;
        pkA = (unsigned)src | ((unsigned)__half_as_ushort(__float2half_rn(v)) << 16);
    }
    if (lane < nB) {
        unsigned eh = bucket[(size_t)nodeB * CAP + lane];
        int src = eh & 0xFFFFu;
        int sn; float sdv; unpack_pd(packed[src], sn, sdv);
        float v = hu2f((unsigned short)(eh >> 16)) * sdv;
        pkB = (unsigned)src | ((unsigned)__half_as_ushort(__float2half_rn(v)) << 16);
    }
    int pkiA = (int)pkA, pkiB = (int)pkB;

    float2 xsA = fp8x2_f32(xs16[(size_t)nodeA * 64 + lane]);
    float2 xsB = fp8x2_f32(xs16[(size_t)nodeB * 64 + lane]);
    float aAx = dvA * xsA.x, aAy = dvA * xsA.y;
    float aBx = dvB * xsB.x, aBy = dvB * xsB.y;

    int nmax = nA > nB ? nA : nB;
    for (int i = 0; i < nmax; i += 8) {
        unsigned av[8], bv[8];
#pragma unroll
        for (int j = 0; j < 8; j++) {
            av[j] = (unsigned)__shfl(pkiA, i + j);
            bv[j] = (unsigned)__shfl(pkiB, i + j);
        }
        unsigned short mA[8], mB[8];
#pragma unroll
        for (int j = 0; j < 8; j++) mA[j] = xs16[(size_t)(av[j] & 0xFFFFu) * 64 + lane];
#pragma unroll
        for (int j = 0; j < 8; j++) mB[j] = xs16[(size_t)(bv[j] & 0xFFFFu) * 64 + lane];
#pragma unroll
        for (int j = 0; j < 8; j++) {
            float2 f = fp8x2_f32(mA[j]);
            float v = hu2f((unsigned short)(av[j] >> 16));
            aAx += v * f.x; aAy += v * f.y;
        }
#pragma unroll
        for (int j = 0; j < 8; j++) {
            float2 f = fp8x2_f32(mB[j]);
            float v = hu2f((unsigned short)(bv[j] >> 16));
            aBx += v * f.x; aBy += v * f.y;
        }
    }

    float hAx = fmaxf(dvA * aAx + bb.x, 0.0f);
    float hAy = fmaxf(dvA * aAy + bb.y, 0.0f);
    float hBx = fmaxf(dvB * aBx + bb.x, 0.0f);
    float hBy = fmaxf(dvB * aBy + bb.y, 0.0f);
    sh1[wv * 2][lane * 2]         = (_Float16)hAx;
    sh1[wv * 2][lane * 2 + 1]     = (_Float16)hAy;
    sh1[wv * 2 + 1][lane * 2]     = (_Float16)hBx;
    sh1[wv * 2 + 1][lane * 2 + 1] = (_Float16)hBy;
    __syncthreads();

    // --- MFMA: rows node0..node0+15; wave wv computes col-tile wv (16 cols).
    const int quad = lane >> 4;
    const int l16  = lane & 15;
    float4v acc0 = {};
#pragma unroll
    for (int kc = 0; kc < 4; kc++) {
        const int k0 = kc * 32;
        half8 a = *(const half8*)(&sh1[l16][k0 + quad * 8]);
        const float* wp = W2 + (size_t)(k0 + quad * 8) * 128 + wv * 16 + l16;
        half8 b;
#pragma unroll
        for (int jj = 0; jj < 8; jj++) b[jj] = (_Float16)wp[jj * 128];
        acc0 = __builtin_amdgcn_mfma_f32_16x16x32_f16(a, b, acc0, 0, 0, 0);
    }
#pragma unroll
    for (int r = 0; r < 4; r++) {
        int row = node0 + quad * 4 + r;
        int rn; float s;
        unpack_pd(packed[row], rn, s);
        x2[(size_t)row * 128 + wv * 16 + l16] = f32_fp8(acc0[r] * s);
    }
}

// ---------------------------------------------------------------------------
// Layer-2 agg + head dot, 2-node interleaved per wave (8 nodes/block,
// 6250 blocks). 8-edge chunks -> 16 independent gathers in flight.
// ---------------------------------------------------------------------------
__global__ __launch_bounds__(256) void agg_head_kernel(const unsigned char* __restrict__ x8,
                                                       const unsigned long long* __restrict__ packed,
                                                       const unsigned int* __restrict__ bucket,
                                                       const float* __restrict__ bias,
                                                       const float* __restrict__ Wh,
                                                       float* __restrict__ nodedot) {
    const int wv   = threadIdx.x >> 6;
    const int lane = threadIdx.x & 63;
    const unsigned short* xs16 = (const unsigned short*)x8;

    const int nodeA = blockIdx.x * 8 + wv * 2;
    const int nodeB = nodeA + 1;
    int nA; float dvA; unpack_pd(packed[nodeA], nA, dvA);
    int nB; float dvB; unpack_pd(packed[nodeB], nB, dvB);

    unsigned ehA = (lane < nA) ? bucket[(size_t)nodeA * CAP + lane] : 0u;
    unsigned ehB = (lane < nB) ? bucket[(size_t)nodeB * CAP + lane] : 0u;
    int eiA = (int)ehA, eiB = (int)ehB;

    float2 xsA = fp8x2_f32(xs16[(size_t)nodeA * 64 + lane]);
    float2 xsB = fp8x2_f32(xs16[(size_t)nodeB * 64 + lane]);
    float aAx = xsA.x, aAy = xsA.y;
    float aBx = xsB.x, aBy = xsB.y;

    int nmax = nA > nB ? nA : nB;
    for (int i = 0; i < nmax; i += 8) {
        unsigned av[8], bv[8];
#pragma unroll
        for (int j = 0; j < 8; j++) {
            av[j] = (unsigned)__shfl(eiA, i + j);
            bv[j] = (unsigned)__shfl(eiB, i + j);
        }
        unsigned short mA[8], mB[8];
#pragma unroll
        for (int j = 0; j < 8; j++) mA[j] = xs16[(size_t)(av[j] & 0xFFFFu) * 64 + lane];
#pragma unroll
        for (int j = 0; j < 8; j++) mB[j] = xs16[(size_t)(bv[j] & 0xFFFFu) * 64 + lane];
#pragma unroll
        for (int j = 0; j < 8; j++) {
            float2 f = fp8x2_f32(mA[j]);
            float v = hu2f((unsigned short)(av[j] >> 16));
            aAx += v * f.x; aAy += v * f.y;
        }
#pragma unroll
        for (int j = 0; j < 8; j++) {
            float2 f = fp8x2_f32(mB[j]);
            float v = hu2f((unsigned short)(bv[j] >> 16));
            aBx += v * f.x; aBy += v * f.y;
        }
    }

    float2 b = ((const float2*)bias)[lane];
    float2 w = ((const float2*)Wh)[lane];
    float hAx = fmaxf(dvA * aAx + b.x, 0.0f);
    float hAy = fmaxf(dvA * aAy + b.y, 0.0f);
    float hBx = fmaxf(dvB * aBx + b.x, 0.0f);
    float hBy = fmaxf(dvB * aBy + b.y, 0.0f);
    float sA = hAx * w.x + hAy * w.y;
    float sB = hBx * w.x + hBy * w.y;
#pragma unroll
    for (int off = 32; off > 0; off >>= 1) {
        sA += __shfl_down(sA, off, 64);
        sB += __shfl_down(sB, off, 64);
    }
    if (lane == 0) {
        nodedot[nodeA] = sA;
        nodedot[nodeB] = sB;
    }
}

// ---------------------------------------------------------------------------
// out[g] = (sum nodedot over graph)/cnt + bh; bounds via binary search.
// ---------------------------------------------------------------------------
__global__ __launch_bounds__(256) void final2_kernel(const float* __restrict__ nodedot,
                                                     const int* __restrict__ batch,
                                                     const float* __restrict__ bh,
                                                     float* __restrict__ out) {
    __shared__ float red[256];
    int g = blockIdx.x;
    int lo = 0, hi = N_NODES;
    while (lo < hi) { int mid = (lo + hi) >> 1; if (batch[mid] < g) lo = mid + 1; else hi = mid; }
    int a = lo;
    hi = N_NODES;
    while (lo < hi) { int mid = (lo + hi) >> 1; if (batch[mid] < g + 1) lo = mid + 1; else hi = mid; }
    int b = lo;

    float s = 0.0f;
    for (int n = a + threadIdx.x; n < b; n += 256) s += nodedot[n];
    red[threadIdx.x] = s;
    __syncthreads();
#pragma unroll
    for (int off = 128; off > 0; off >>= 1) {
        if (threadIdx.x < off) red[threadIdx.x] += red[threadIdx.x + off];
        __syncthreads();
    }
    if (threadIdx.x == 0)
        out[g] = red[0] / fmaxf((float)(b - a), 1.0f) + bh[0];
}

// ---------------------------------------------------------------------------
extern "C" void kernel_launch(void* const* d_in, const int* in_sizes, int n_in,
                              void* d_out, int out_size, void* d_ws, size_t ws_size,
                              hipStream_t stream) {
    const float* x   = (const float*)d_in[0];
    const float* ew  = (const float*)d_in[1];
    const float* W1  = (const float*)d_in[2];
    const float* b1  = (const float*)d_in[3];
    const float* W2  = (const float*)d_in[4];
    const float* b2  = (const float*)d_in[5];
    const float* Wh  = (const float*)d_in[6];
    const float* bh  = (const float*)d_in[7];
    const int*   ei  = (const int*)d_in[8];
    const int*   bat = (const int*)d_in[9];
    float* out = (float*)d_out;

    char* ws = (char*)d_ws;
    unsigned char* bufA8 = (unsigned char*)ws;            ws += (size_t)N_NODES * D;
    unsigned char* bufB8 = (unsigned char*)ws;            ws += (size_t)N_NODES * D;
    ws += 128 - ((size_t)ws & 127);                       // realign
    unsigned int* bucket = (unsigned int*)ws;             ws += (size_t)N_NODES * CAP * 4;
    unsigned long long* packed = (unsigned long long*)ws; ws += (size_t)N_NODES * 8;
    float*  nodedot = (float*)ws;                         ws += (size_t)N_NODES * 4;

    const int nb_agg8 = N_NODES / 8;                  // 6250

    hipMemsetAsync(packed, 0, (size_t)N_NODES * 8, stream);

    // gemm1 (x@W1 -> fp8 via MFMA fp16) overlapped with fill (atomic-floor-bound)
    fused_gemm1_fill<<<NB_GEMM1 + NB_FILL, 256, 0, stream>>>(x, W1, bufA8, ei, ew, packed, bucket);

    // layer 1 agg (2-node interleave, 16 gathers in flight) + gemm2 -> x2' fp8
    agg1_gemm2_kernel<<<NB_AGG16, 512, 0, stream>>>(bufA8, packed, bucket, b1, W2, bufB8);

    // layer 2 agg (2-node interleave, 16 gathers in flight) + head dot
    agg_head_kernel<<<nb_agg8, 256, 0, stream>>>(bufB8, packed, bucket, b2, Wh, nodedot);

    // segment-sum + head bias
    final2_kernel<<<N_GRAPHS, 256, 0, stream>>>(nodedot, bat, bh, out);
}